// Round 4
// baseline (240.519 us; speedup 1.0000x reference)
//
#include <hip/hip_runtime.h>

// VectorQuantizer: x[128,512,64] f32, codebook[1024,64] f32
// outputs (flat in d_out, float32): quantized[4194304], loss[1], indices[65536]
//
// R4: MFMA screening. Split x=xh+xl, c=ch+cl (bf16); screen key via K=192
// bf16 GEMM (xh.ch + xh.cl + xl.ch), fused per-lane top-2 argmin.
// Screen error <= ~6e-3 worst case; rows with top-2 gap <= TAU=0.05 get a
// full fp64 recheck -> argmin fp64-exact. Loss reduced fp64, fixed order.
// xw (bf16 x, 16MB) staged in d_out's quantized region (k4 overwrites later).

typedef __attribute__((ext_vector_type(8))) short bf16x8;
typedef __attribute__((ext_vector_type(4))) float f32x4;
typedef __attribute__((ext_vector_type(8))) unsigned short u16x8;

static constexpr int Vn    = 1024;
static constexpr int Hn    = 64;
static constexpr int Nrows = 128 * 512;          // 65536
static constexpr int QSZ   = Nrows * Hn;         // 4194304
#define TAU 0.05f

__device__ inline unsigned short f2bf(float f) {         // RNE fp32->bf16
  unsigned u = __float_as_uint(f);
  return (unsigned short)((u + 0x7fffu + ((u >> 16) & 1u)) >> 16);
}
__device__ inline float bf2f(unsigned short h) {
  return __uint_as_float(((unsigned)h) << 16);
}

// ---- ws layout (bytes) ----
// 0      : double cnormd[1024]       (8192)
// 8192   : double partials[4096]     (32768)
// 40960  : float  cnormf[1024]       (4096)
// 45056  : int    bestIdx[65536]     (262144)
// 307200 : int    flagCount          (8)
// 307208 : int    flagList[65536]    (262144)
// 573440 : ushort cw[1024*128]       (262144)   [ch(64)|cl(64)] per code
// total ~836 KB

// Codebook prep: fp64 norms + bf16 hi/lo split.
__global__ __launch_bounds__(256) void kC(
    const float* __restrict__ cb, unsigned short* __restrict__ cw,
    double* __restrict__ cnd, float* __restrict__ cnf,
    int* __restrict__ flagCount) {
  int v = blockIdx.x * 256 + threadIdx.x;
  if (v == 0) *flagCount = 0;
  if (v >= Vn) return;
  const float* c = cb + v * Hn;
  double s = 0;
  unsigned short hs[64], ls[64];
  for (int k = 0; k < 64; ++k) {
    float f = c[k];
    s += (double)f * (double)f;
    unsigned short h = f2bf(f);
    hs[k] = h;
    ls[k] = f2bf(f - bf2f(h));
  }
  cnd[v] = s;
  cnf[v] = (float)s;
  u16x8* dst = (u16x8*)(cw + v * 128);
#pragma unroll
  for (int k = 0; k < 8; ++k) {
    u16x8 a; for (int j = 0; j < 8; ++j) a[j] = hs[k * 8 + j];
    dst[k] = a;
  }
#pragma unroll
  for (int k = 0; k < 8; ++k) {
    u16x8 a; for (int j = 0; j < 8; ++j) a[j] = ls[k * 8 + j];
    dst[8 + k] = a;
  }
}

// x prep: [row][128] = [xh(64)|xl(64)] bf16, written into d_out's q-region.
__global__ __launch_bounds__(256) void kP(const float* __restrict__ x,
                                          unsigned short* __restrict__ xw) {
  const int t = blockIdx.x * 256 + threadIdx.x;  // Nrows*4 threads
  const int row = t >> 2, seg = t & 3;
  const float4* src = (const float4*)(x + (long)row * 64 + seg * 16);
  unsigned short hs[16], ls[16];
#pragma unroll
  for (int q = 0; q < 4; ++q) {
    float4 f = src[q];
    float vv[4] = {f.x, f.y, f.z, f.w};
#pragma unroll
    for (int j = 0; j < 4; ++j) {
      unsigned short h = f2bf(vv[j]);
      hs[q * 4 + j] = h;
      ls[q * 4 + j] = f2bf(vv[j] - bf2f(h));
    }
  }
  u16x8 a, b;
#pragma unroll
  for (int j = 0; j < 8; ++j) { a[j] = hs[j]; b[j] = hs[8 + j]; }
  u16x8* d1 = (u16x8*)(xw + (long)row * 128 + seg * 16);
  d1[0] = a; d1[1] = b;
#pragma unroll
  for (int j = 0; j < 8; ++j) { a[j] = ls[j]; b[j] = ls[8 + j]; }
  u16x8* d2 = (u16x8*)(xw + (long)row * 128 + 64 + seg * 16);
  d2[0] = a; d2[1] = b;
}

// Fused MFMA screen + argmin. Block = 4 waves, 32 rows; wave w sweeps codes
// [256w, 256w+256) as 16 code-tiles of 16. Per 16x16 tile: K=192 via 6 MFMA.
// A frag: row=lane&15, k=(lane>>4)*8+j. B frag: col=lane&15, same k-map.
// C frag: col=lane&15, row=4*(lane>>4)+reg (m89-verified).
__global__ __launch_bounds__(256, 3) void kMF(
    const unsigned short* __restrict__ xw, const unsigned short* __restrict__ cw,
    const float* __restrict__ cnf, int* __restrict__ bestIdx,
    int* __restrict__ flagCount, int* __restrict__ flagList,
    float* __restrict__ outIdx) {
  __shared__ float sB1[4][32], sB2[4][32];
  __shared__ int   sI[4][32];
  const int tid = threadIdx.x;
  const int lane = tid & 63;
  const int w = tid >> 6;
  const int l15 = lane & 15, g = lane >> 4;
  const int rowBase = blockIdx.x * 32;

  // A fragments: 2 row-tiles x {xh0,xh1,xl0,xl1}, resident all loop long.
  bf16x8 A[2][4];
#pragma unroll
  for (int rt = 0; rt < 2; ++rt) {
    const unsigned short* ar = xw + (long)(rowBase + rt * 16 + l15) * 128 + g * 8;
    A[rt][0] = *(const bf16x8*)(ar + 0);
    A[rt][1] = *(const bf16x8*)(ar + 32);
    A[rt][2] = *(const bf16x8*)(ar + 64);
    A[rt][3] = *(const bf16x8*)(ar + 96);
  }

  float b1[2][4], b2[2][4];
  int   bi[2][4];
#pragma unroll
  for (int rt = 0; rt < 2; ++rt)
#pragma unroll
    for (int r = 0; r < 4; ++r) { b1[rt][r] = 3.4e38f; b2[rt][r] = 3.4e38f; bi[rt][r] = 0; }

  const int codeBase = w * 256;
  for (int ct = 0; ct < 16; ++ct) {
    const int c0 = codeBase + ct * 16;
    const unsigned short* br = cw + (long)(c0 + l15) * 128 + g * 8;
    bf16x8 Bh0 = *(const bf16x8*)(br + 0);
    bf16x8 Bh1 = *(const bf16x8*)(br + 32);
    bf16x8 Bl0 = *(const bf16x8*)(br + 64);
    bf16x8 Bl1 = *(const bf16x8*)(br + 96);
    const float cnfv = cnf[c0 + l15];
    const int v = c0 + l15;
#pragma unroll
    for (int rt = 0; rt < 2; ++rt) {
      f32x4 acc = {0.f, 0.f, 0.f, 0.f};
      acc = __builtin_amdgcn_mfma_f32_16x16x32_bf16(A[rt][0], Bh0, acc, 0, 0, 0); // xh.ch
      acc = __builtin_amdgcn_mfma_f32_16x16x32_bf16(A[rt][1], Bh1, acc, 0, 0, 0);
      acc = __builtin_amdgcn_mfma_f32_16x16x32_bf16(A[rt][0], Bl0, acc, 0, 0, 0); // xh.cl
      acc = __builtin_amdgcn_mfma_f32_16x16x32_bf16(A[rt][1], Bl1, acc, 0, 0, 0);
      acc = __builtin_amdgcn_mfma_f32_16x16x32_bf16(A[rt][2], Bh0, acc, 0, 0, 0); // xl.ch
      acc = __builtin_amdgcn_mfma_f32_16x16x32_bf16(A[rt][3], Bh1, acc, 0, 0, 0);
#pragma unroll
      for (int r = 0; r < 4; ++r) {
        float key = fmaf(-2.0f, acc[r], cnfv);
        bool lt = key < b1[rt][r];
        float worse = fmaxf(key, b1[rt][r]);
        b2[rt][r] = fminf(b2[rt][r], worse);
        b1[rt][r] = fminf(b1[rt][r], key);
        bi[rt][r] = lt ? v : bi[rt][r];
      }
    }
  }

  // Merge top-2 across the 16 lanes holding each row (cols 0..15 subsets).
#pragma unroll
  for (int rt = 0; rt < 2; ++rt)
#pragma unroll
    for (int r = 0; r < 4; ++r) {
      float B1r = b1[rt][r], B2r = b2[rt][r];
      int Ir = bi[rt][r];
#pragma unroll
      for (int m = 1; m < 16; m <<= 1) {
        float o1 = __shfl_xor(B1r, m), o2 = __shfl_xor(B2r, m);
        int oi = __shfl_xor(Ir, m);
        float worse = fmaxf(B1r, o1);
        B2r = fminf(fminf(B2r, o2), worse);
        bool take = (o1 < B1r) || (o1 == B1r && oi < Ir);
        B1r = take ? o1 : B1r;
        Ir  = take ? oi : Ir;
      }
      b1[rt][r] = B1r; b2[rt][r] = B2r; bi[rt][r] = Ir;
    }

  // Writers: lane with l15==r publishes row rt*16 + 4g + r (static reg idx).
#pragma unroll
  for (int rt = 0; rt < 2; ++rt)
#pragma unroll
    for (int r = 0; r < 4; ++r)
      if (l15 == r) {
        int rowIn = rt * 16 + 4 * g + r;
        sB1[w][rowIn] = b1[rt][r];
        sB2[w][rowIn] = b2[rt][r];
        sI[w][rowIn]  = bi[rt][r];
      }
  __syncthreads();

  if (tid < 32) {
    float B1 = sB1[0][tid], B2 = sB2[0][tid];
    int I = sI[0][tid];
#pragma unroll
    for (int ww = 1; ww < 4; ++ww) {
      float o1 = sB1[ww][tid], o2 = sB2[ww][tid];
      int oi = sI[ww][tid];
      float worse = fmaxf(B1, o1);
      B2 = fminf(fminf(B2, o2), worse);
      bool take = (o1 < B1) || (o1 == B1 && oi < I);
      B1 = take ? o1 : B1;
      I  = take ? oi : I;
    }
    const int row = rowBase + tid;
    bestIdx[row] = I;
    outIdx[row] = (float)I;
    if (B2 - B1 <= TAU) {
      int slot = atomicAdd(flagCount, 1);
      flagList[slot] = row;                      // order-independent use
    }
  }
}

// fp64 recheck of flagged rows (all 1024 codes), first-min tie-break.
__global__ __launch_bounds__(256) void k3_recheck(
    const float* __restrict__ x, const float* __restrict__ cb,
    const double* __restrict__ cnd, int* __restrict__ bestIdx,
    const int* __restrict__ flagCount, const int* __restrict__ flagList,
    float* __restrict__ outIdx) {
  __shared__ float xs[64];
  __shared__ double rk[256];
  __shared__ int    ri[256];
  const int tid = threadIdx.x;
  const int cnt = *flagCount;

  for (int jj = blockIdx.x; jj < cnt; jj += gridDim.x) {
    const int row = flagList[jj];
    if (tid < 16)
      reinterpret_cast<float4*>(xs)[tid] =
          reinterpret_cast<const float4*>(x + (long)row * Hn)[tid];
    __syncthreads();

    double bk = 1e300;
    int bi = 0;
#pragma unroll
    for (int cc = 0; cc < 4; ++cc) {
      const int v = cc * 256 + tid;              // ascending per thread
      const float4* c4 = reinterpret_cast<const float4*>(cb + v * Hn);
      double a0 = 0, a1 = 0, a2 = 0, a3 = 0;
#pragma unroll
      for (int k = 0; k < 16; ++k) {
        float4 f = c4[k];
        a0 += (double)f.x * (double)xs[4 * k + 0];
        a1 += (double)f.y * (double)xs[4 * k + 1];
        a2 += (double)f.z * (double)xs[4 * k + 2];
        a3 += (double)f.w * (double)xs[4 * k + 3];
      }
      double dot = (a0 + a1) + (a2 + a3);
      double key = cnd[v] - 2.0 * dot;
      if (key < bk) { bk = key; bi = v; }
    }
    rk[tid] = bk; ri[tid] = bi;
    __syncthreads();
    for (int s = 128; s > 0; s >>= 1) {
      if (tid < s) {
        if (rk[tid + s] < rk[tid] ||
            (rk[tid + s] == rk[tid] && ri[tid + s] < ri[tid])) {
          rk[tid] = rk[tid + s]; ri[tid] = ri[tid + s];
        }
      }
      __syncthreads();
    }
    if (tid == 0) {
      bestIdx[row] = ri[0];
      outIdx[row] = (float)ri[0];
    }
    __syncthreads();
  }
}

// Gather quantized (overwrites the xw staging region) + fp64 loss partials.
__global__ __launch_bounds__(256) void k4_gather(
    const float* __restrict__ x, const float* __restrict__ cb,
    const int* __restrict__ bestIdx, float* __restrict__ out,
    double* __restrict__ partials) {
  __shared__ double red[256];
  const int t = blockIdx.x * 256 + threadIdx.x;  // float4 index
  const int i = t * 4;
  const int row = i >> 6;
  const int h4 = (i & 63) >> 2;
  const int idx = bestIdx[row];
  float4 q  = reinterpret_cast<const float4*>(cb)[idx * 16 + h4];
  float4 xv = reinterpret_cast<const float4*>(x)[t];
  reinterpret_cast<float4*>(out)[t] = q;
  double dx = (double)q.x - (double)xv.x;
  double dy = (double)q.y - (double)xv.y;
  double dz = (double)q.z - (double)xv.z;
  double dw = (double)q.w - (double)xv.w;
  red[threadIdx.x] = dx * dx + dy * dy + dz * dz + dw * dw;
  __syncthreads();
  for (int s = 128; s > 0; s >>= 1) {
    if (threadIdx.x < s) red[threadIdx.x] += red[threadIdx.x + s];
    __syncthreads();
  }
  if (threadIdx.x == 0) partials[blockIdx.x] = red[0];
}

__global__ __launch_bounds__(256) void k6_loss(const double* __restrict__ partials,
                                               float* __restrict__ out) {
  __shared__ double red[256];
  double a = 0;
  for (int k = threadIdx.x; k < 4096; k += 256) a += partials[k];  // fixed order
  red[threadIdx.x] = a;
  __syncthreads();
  for (int s = 128; s > 0; s >>= 1) {
    if (threadIdx.x < s) red[threadIdx.x] += red[threadIdx.x + s];
    __syncthreads();
  }
  if (threadIdx.x == 0)
    out[QSZ] = (float)(1.25 * red[0] / (double)QSZ);
}

extern "C" void kernel_launch(void* const* d_in, const int* in_sizes, int n_in,
                              void* d_out, int out_size, void* d_ws, size_t ws_size,
                              hipStream_t stream) {
  const float* x  = (const float*)d_in[0];
  const float* cb = (const float*)d_in[1];
  float* out = (float*)d_out;
  char* ws = (char*)d_ws;

  double* cnd      = (double*)(ws + 0);
  double* partials = (double*)(ws + 8192);
  float*  cnf      = (float*) (ws + 40960);
  int*    bestIdx  = (int*)   (ws + 45056);
  int*    flagCnt  = (int*)   (ws + 307200);
  int*    flagList = (int*)   (ws + 307208);
  unsigned short* cw = (unsigned short*)(ws + 573440);

  unsigned short* xw = (unsigned short*)d_out;   // staged in q-region (16MB)
  float* outIdx = out + QSZ + 1;

  kC        <<<4,    256, 0, stream>>>(cb, cw, cnd, cnf, flagCnt);
  kP        <<<1024, 256, 0, stream>>>(x, xw);
  kMF       <<<2048, 256, 0, stream>>>(xw, cw, cnf, bestIdx, flagCnt, flagList, outIdx);
  k3_recheck<<<128,  256, 0, stream>>>(x, cb, cnd, bestIdx, flagCnt, flagList, outIdx);
  k4_gather <<<4096, 256, 0, stream>>>(x, cb, bestIdx, out, partials);
  k6_loss   <<<1,    256, 0, stream>>>(partials, out);
}

// Round 5
// 164.179 us; speedup vs baseline: 1.4650x; 1.4650x over previous
//
#include <hip/hip_runtime.h>

// VectorQuantizer: x[128,512,64] f32, codebook[1024,64] f32
// outputs (flat in d_out, float32): quantized[4194304], loss[1], indices[65536]
//
// R5: MFMA screen (split-bf16, K=192) with 64 rows/block (4 row-tiles/wave:
// 4x MFMA ILP, half the codebook L2 traffic) + in-kernel x->bf16 conversion
// (kP deleted). k3 rewritten: fp32 exact sweep + selective fp64 only for
// codes within MARGIN of the row min -> argmin fp64-exact, no fp64 wall.
// Loss reduced fp64, fixed order (deterministic).

typedef __attribute__((ext_vector_type(8))) short bf16x8;
typedef __attribute__((ext_vector_type(4))) float f32x4;
typedef __attribute__((ext_vector_type(8))) unsigned short u16x8;

static constexpr int Vn    = 1024;
static constexpr int Hn    = 64;
static constexpr int Nrows = 128 * 512;          // 65536
static constexpr int QSZ   = Nrows * Hn;         // 4194304
#define TAU 0.05f
#define MARGIN 4e-3f

__device__ inline unsigned short f2bf(float f) {         // RNE fp32->bf16
  unsigned u = __float_as_uint(f);
  return (unsigned short)((u + 0x7fffu + ((u >> 16) & 1u)) >> 16);
}
__device__ inline float bf2f(unsigned short h) {
  return __uint_as_float(((unsigned)h) << 16);
}

// ---- ws layout (bytes) ----
// 0      : double cnormd[1024]       (8192)
// 8192   : double partials[4096]     (32768)
// 40960  : float  cnormf[1024]       (4096)
// 45056  : int    bestIdx[65536]     (262144)
// 307200 : int    flagCount          (8)
// 307208 : int    flagList[65536]    (262144)
// 573440 : ushort cw[1024*128]       (262144)   [ch(64)|cl(64)] per code

// Codebook prep: fp64 norms + bf16 hi/lo split.
__global__ __launch_bounds__(256) void kC(
    const float* __restrict__ cb, unsigned short* __restrict__ cw,
    double* __restrict__ cnd, float* __restrict__ cnf,
    int* __restrict__ flagCount) {
  int v = blockIdx.x * 256 + threadIdx.x;
  if (v == 0) *flagCount = 0;
  if (v >= Vn) return;
  const float* c = cb + v * Hn;
  double s = 0;
  unsigned short hs[64], ls[64];
  for (int k = 0; k < 64; ++k) {
    float f = c[k];
    s += (double)f * (double)f;
    unsigned short h = f2bf(f);
    hs[k] = h;
    ls[k] = f2bf(f - bf2f(h));
  }
  cnd[v] = s;
  cnf[v] = (float)s;
  u16x8* dst = (u16x8*)(cw + v * 128);
#pragma unroll
  for (int k = 0; k < 8; ++k) {
    u16x8 a; for (int j = 0; j < 8; ++j) a[j] = hs[k * 8 + j];
    dst[k] = a;
  }
#pragma unroll
  for (int k = 0; k < 8; ++k) {
    u16x8 a; for (int j = 0; j < 8; ++j) a[j] = ls[k * 8 + j];
    dst[8 + k] = a;
  }
}

// Fused MFMA screen + argmin. Block = 4 waves, 64 rows (4 row-tiles); wave w
// sweeps codes [256w, 256w+256) as 16 code-tiles. Per 16x16 tile: K=192 via
// 6 MFMA (xh.ch + xh.cl + xl.ch), 4 independent acc chains (one per rt).
// A frag: row=lane&15, k=(lane>>4)*8+j (x converted to bf16 hi/lo in-kernel).
// C frag: col=lane&15, row=4*(lane>>4)+reg (m89-verified; validated R4).
__global__ __launch_bounds__(256, 2) void kMF(
    const float* __restrict__ x, const unsigned short* __restrict__ cw,
    const float* __restrict__ cnf, int* __restrict__ bestIdx,
    int* __restrict__ flagCount, int* __restrict__ flagList,
    float* __restrict__ outIdx) {
  __shared__ float sB1[4][64], sB2[4][64];
  __shared__ int   sI[4][64];
  const int tid = threadIdx.x;
  const int lane = tid & 63;
  const int w = tid >> 6;
  const int l15 = lane & 15, g = lane >> 4;
  const int rowBase = blockIdx.x * 64;

  // A fragments: 4 row-tiles x {xh0,xh1,xl0,xl1}, converted from f32 here.
  bf16x8 A[4][4];
#pragma unroll
  for (int rt = 0; rt < 4; ++rt) {
    const float* xr = x + (long)(rowBase + rt * 16 + l15) * Hn + g * 8;
    float4 fa0 = *(const float4*)(xr + 0);
    float4 fa1 = *(const float4*)(xr + 4);
    float4 fb0 = *(const float4*)(xr + 32);
    float4 fb1 = *(const float4*)(xr + 36);
    float va[8] = {fa0.x, fa0.y, fa0.z, fa0.w, fa1.x, fa1.y, fa1.z, fa1.w};
    float vb[8] = {fb0.x, fb0.y, fb0.z, fb0.w, fb1.x, fb1.y, fb1.z, fb1.w};
    bf16x8 h0, h1, l0, l1;
#pragma unroll
    for (int j = 0; j < 8; ++j) {
      unsigned short h = f2bf(va[j]);
      h0[j] = (short)h;
      l0[j] = (short)f2bf(va[j] - bf2f(h));
      unsigned short h2 = f2bf(vb[j]);
      h1[j] = (short)h2;
      l1[j] = (short)f2bf(vb[j] - bf2f(h2));
    }
    A[rt][0] = h0; A[rt][1] = h1; A[rt][2] = l0; A[rt][3] = l1;
  }

  float b1[4][4], b2[4][4];
  int   bi[4][4];
#pragma unroll
  for (int rt = 0; rt < 4; ++rt)
#pragma unroll
    for (int r = 0; r < 4; ++r) { b1[rt][r] = 3.4e38f; b2[rt][r] = 3.4e38f; bi[rt][r] = 0; }

  const int codeBase = w * 256;
  for (int ct = 0; ct < 16; ++ct) {
    const int c0 = codeBase + ct * 16;
    const unsigned short* br = cw + (long)(c0 + l15) * 128 + g * 8;
    bf16x8 Bh0 = *(const bf16x8*)(br + 0);
    bf16x8 Bh1 = *(const bf16x8*)(br + 32);
    bf16x8 Bl0 = *(const bf16x8*)(br + 64);
    bf16x8 Bl1 = *(const bf16x8*)(br + 96);
    const float cnfv = cnf[c0 + l15];
    const int v = c0 + l15;
#pragma unroll
    for (int rt = 0; rt < 4; ++rt) {
      f32x4 acc = {0.f, 0.f, 0.f, 0.f};
      acc = __builtin_amdgcn_mfma_f32_16x16x32_bf16(A[rt][0], Bh0, acc, 0, 0, 0); // xh.ch
      acc = __builtin_amdgcn_mfma_f32_16x16x32_bf16(A[rt][1], Bh1, acc, 0, 0, 0);
      acc = __builtin_amdgcn_mfma_f32_16x16x32_bf16(A[rt][0], Bl0, acc, 0, 0, 0); // xh.cl
      acc = __builtin_amdgcn_mfma_f32_16x16x32_bf16(A[rt][1], Bl1, acc, 0, 0, 0);
      acc = __builtin_amdgcn_mfma_f32_16x16x32_bf16(A[rt][2], Bh0, acc, 0, 0, 0); // xl.ch
      acc = __builtin_amdgcn_mfma_f32_16x16x32_bf16(A[rt][3], Bh1, acc, 0, 0, 0);
#pragma unroll
      for (int r = 0; r < 4; ++r) {
        float key = fmaf(-2.0f, acc[r], cnfv);
        bool lt = key < b1[rt][r];
        b2[rt][r] = __builtin_amdgcn_fmed3f(key, b1[rt][r], b2[rt][r]); // 2nd-best
        b1[rt][r] = fminf(b1[rt][r], key);
        bi[rt][r] = lt ? v : bi[rt][r];
      }
    }
  }

  // Merge top-2 across the 16 lanes holding each row (cols 0..15 subsets).
#pragma unroll
  for (int rt = 0; rt < 4; ++rt)
#pragma unroll
    for (int r = 0; r < 4; ++r) {
      float B1r = b1[rt][r], B2r = b2[rt][r];
      int Ir = bi[rt][r];
#pragma unroll
      for (int m = 1; m < 16; m <<= 1) {
        float o1 = __shfl_xor(B1r, m), o2 = __shfl_xor(B2r, m);
        int oi = __shfl_xor(Ir, m);
        float worse = fmaxf(B1r, o1);
        B2r = fminf(fminf(B2r, o2), worse);
        bool take = (o1 < B1r) || (o1 == B1r && oi < Ir);
        B1r = take ? o1 : B1r;
        Ir  = take ? oi : Ir;
      }
      b1[rt][r] = B1r; b2[rt][r] = B2r; bi[rt][r] = Ir;
    }

  // Writers: lane with l15==r publishes row rt*16 + 4g + r (static reg idx).
#pragma unroll
  for (int rt = 0; rt < 4; ++rt)
#pragma unroll
    for (int r = 0; r < 4; ++r)
      if (l15 == r) {
        int rowIn = rt * 16 + 4 * g + r;
        sB1[w][rowIn] = b1[rt][r];
        sB2[w][rowIn] = b2[rt][r];
        sI[w][rowIn]  = bi[rt][r];
      }
  __syncthreads();

  if (tid < 64) {
    float B1 = sB1[0][tid], B2 = sB2[0][tid];
    int I = sI[0][tid];
#pragma unroll
    for (int ww = 1; ww < 4; ++ww) {
      float o1 = sB1[ww][tid], o2 = sB2[ww][tid];
      int oi = sI[ww][tid];
      float worse = fmaxf(B1, o1);
      B2 = fminf(fminf(B2, o2), worse);
      bool take = (o1 < B1) || (o1 == B1 && oi < I);
      B1 = take ? o1 : B1;
      I  = take ? oi : I;
    }
    const int row = rowBase + tid;
    bestIdx[row] = I;
    outIdx[row] = (float)I;
    if (B2 - B1 <= TAU) {
      int slot = atomicAdd(flagCount, 1);
      flagList[slot] = row;                      // order-independent use
    }
  }
}

// Recheck flagged rows: exact-fp32 sweep of all 1024 codes, then fp64 keys
// only for codes within MARGIN of the fp32 min (|key32-key64| <= ~5e-4).
// fp64 formula identical to R1-R4 (matched np exactly). One row per block.
__global__ __launch_bounds__(256) void k3_recheck(
    const float* __restrict__ x, const float* __restrict__ cb,
    const double* __restrict__ cnd, const float* __restrict__ cnf,
    int* __restrict__ bestIdx,
    const int* __restrict__ flagCount, const int* __restrict__ flagList,
    float* __restrict__ outIdx) {
  __shared__ float xs[64];
  __shared__ float rmin[256];
  __shared__ double dk[256];
  __shared__ int    di[256];
  const int tid = threadIdx.x;
  const int cnt = *flagCount;

  for (int jj = blockIdx.x; jj < cnt; jj += gridDim.x) {
    const int row = flagList[jj];
    if (tid < 16)
      reinterpret_cast<float4*>(xs)[tid] =
          reinterpret_cast<const float4*>(x + (long)row * Hn)[tid];
    __syncthreads();

    // exact fp32 keys for 4 codes/thread
    float key32[4];
#pragma unroll
    for (int cc = 0; cc < 4; ++cc) {
      const int v = cc * 256 + tid;
      const float4* c4 = reinterpret_cast<const float4*>(cb + v * Hn);
      float d0 = 0, d1 = 0, d2 = 0, d3 = 0;
#pragma unroll
      for (int k = 0; k < 16; ++k) {
        float4 f = c4[k];
        d0 = fmaf(f.x, xs[4 * k + 0], d0);
        d1 = fmaf(f.y, xs[4 * k + 1], d1);
        d2 = fmaf(f.z, xs[4 * k + 2], d2);
        d3 = fmaf(f.w, xs[4 * k + 3], d3);
      }
      key32[cc] = cnf[v] - 2.0f * ((d0 + d1) + (d2 + d3));
    }

    // block min of fp32 keys
    float m = fminf(fminf(key32[0], key32[1]), fminf(key32[2], key32[3]));
    rmin[tid] = m;
    __syncthreads();
    for (int s = 128; s > 0; s >>= 1) {
      if (tid < s) rmin[tid] = fminf(rmin[tid], rmin[tid + s]);
      __syncthreads();
    }
    const float m1 = rmin[0];

    // fp64 keys only for candidates within MARGIN of m1
    double bk = 1e300;
    int bidx = 0x7FFFFFFF;
#pragma unroll
    for (int cc = 0; cc < 4; ++cc) {
      if (key32[cc] <= m1 + MARGIN) {
        const int v = cc * 256 + tid;
        const float4* c4 = reinterpret_cast<const float4*>(cb + v * Hn);
        double a0 = 0, a1 = 0, a2 = 0, a3 = 0;
#pragma unroll
        for (int k = 0; k < 16; ++k) {
          float4 f = c4[k];
          a0 += (double)f.x * (double)xs[4 * k + 0];
          a1 += (double)f.y * (double)xs[4 * k + 1];
          a2 += (double)f.z * (double)xs[4 * k + 2];
          a3 += (double)f.w * (double)xs[4 * k + 3];
        }
        double key = cnd[v] - 2.0 * ((a0 + a1) + (a2 + a3));
        if (key < bk || (key == bk && v < bidx)) { bk = key; bidx = v; }
      }
    }
    dk[tid] = bk; di[tid] = bidx;
    __syncthreads();
    for (int s = 128; s > 0; s >>= 1) {
      if (tid < s) {
        if (dk[tid + s] < dk[tid] ||
            (dk[tid + s] == dk[tid] && di[tid + s] < di[tid])) {
          dk[tid] = dk[tid + s]; di[tid] = di[tid + s];
        }
      }
      __syncthreads();
    }
    if (tid == 0) {
      bestIdx[row] = di[0];
      outIdx[row] = (float)di[0];
    }
    __syncthreads();
  }
}

// Gather quantized + fp64 per-block loss partials.
__global__ __launch_bounds__(256) void k4_gather(
    const float* __restrict__ x, const float* __restrict__ cb,
    const int* __restrict__ bestIdx, float* __restrict__ out,
    double* __restrict__ partials) {
  __shared__ double red[256];
  const int t = blockIdx.x * 256 + threadIdx.x;  // float4 index
  const int i = t * 4;
  const int row = i >> 6;
  const int h4 = (i & 63) >> 2;
  const int idx = bestIdx[row];
  float4 q  = reinterpret_cast<const float4*>(cb)[idx * 16 + h4];
  float4 xv = reinterpret_cast<const float4*>(x)[t];
  reinterpret_cast<float4*>(out)[t] = q;
  double dx = (double)q.x - (double)xv.x;
  double dy = (double)q.y - (double)xv.y;
  double dz = (double)q.z - (double)xv.z;
  double dw = (double)q.w - (double)xv.w;
  red[threadIdx.x] = dx * dx + dy * dy + dz * dz + dw * dw;
  __syncthreads();
  for (int s = 128; s > 0; s >>= 1) {
    if (threadIdx.x < s) red[threadIdx.x] += red[threadIdx.x + s];
    __syncthreads();
  }
  if (threadIdx.x == 0) partials[blockIdx.x] = red[0];
}

__global__ __launch_bounds__(256) void k6_loss(const double* __restrict__ partials,
                                               float* __restrict__ out) {
  __shared__ double red[256];
  double a = 0;
  for (int k = threadIdx.x; k < 4096; k += 256) a += partials[k];  // fixed order
  red[threadIdx.x] = a;
  __syncthreads();
  for (int s = 128; s > 0; s >>= 1) {
    if (threadIdx.x < s) red[threadIdx.x] += red[threadIdx.x + s];
    __syncthreads();
  }
  if (threadIdx.x == 0)
    out[QSZ] = (float)(1.25 * red[0] / (double)QSZ);
}

extern "C" void kernel_launch(void* const* d_in, const int* in_sizes, int n_in,
                              void* d_out, int out_size, void* d_ws, size_t ws_size,
                              hipStream_t stream) {
  const float* x  = (const float*)d_in[0];
  const float* cb = (const float*)d_in[1];
  float* out = (float*)d_out;
  char* ws = (char*)d_ws;

  double* cnd      = (double*)(ws + 0);
  double* partials = (double*)(ws + 8192);
  float*  cnf      = (float*) (ws + 40960);
  int*    bestIdx  = (int*)   (ws + 45056);
  int*    flagCnt  = (int*)   (ws + 307200);
  int*    flagList = (int*)   (ws + 307208);
  unsigned short* cw = (unsigned short*)(ws + 573440);

  float* outIdx = out + QSZ + 1;

  kC        <<<4,    256, 0, stream>>>(cb, cw, cnd, cnf, flagCnt);
  kMF       <<<1024, 256, 0, stream>>>(x, cw, cnf, bestIdx, flagCnt, flagList, outIdx);
  k3_recheck<<<2048, 256, 0, stream>>>(x, cb, cnd, cnf, bestIdx, flagCnt, flagList, outIdx);
  k4_gather <<<4096, 256, 0, stream>>>(x, cb, bestIdx, out, partials);
  k6_loss   <<<1,    256, 0, stream>>>(partials, out);
}